// Round 6
// baseline (1311.127 us; speedup 1.0000x reference)
//
#include <hip/hip_runtime.h>
#include <hip/hip_bf16.h>
#include <cstdint>
#include <cstddef>

#define HIDDEN 1024
#define HEADS  16
#define HDIM   64
#define BATCH  2
#define SEQ    2048
#define MTOT   (BATCH*SEQ)   // 4096 rows
#define KSEL   1024          // k_keep = S * (1 - 0.5)
#define QT     16            // q rows per attention block

typedef __attribute__((ext_vector_type(8))) short bf16x8;
typedef __attribute__((ext_vector_type(4))) float f32x4;

__device__ __forceinline__ unsigned short f2bf_rne(float f) {
    unsigned u = __float_as_uint(f);
    u += 0x7fffu + ((u >> 16) & 1u);
    return (unsigned short)(u >> 16);
}
__device__ __forceinline__ float bf2f(unsigned short h) {
    return __uint_as_float(((unsigned)h) << 16);
}
__device__ __forceinline__ int score_bucket(float v) {
    int b = (int)floorf(__fmaf_rn(v, 32.0f, 256.0f));
    return min(511, max(0, b));
}
__device__ __forceinline__ void gl2lds16(const unsigned short* g, unsigned short* l) {
    __builtin_amdgcn_global_load_lds(
        (const __attribute__((address_space(1))) unsigned int*)g,
        (__attribute__((address_space(3))) unsigned int*)l, 16, 0, 0);
}

// ---------------------------------------------------------------------------
// fp32 -> bf16 hi/lo split (memory-bound prep)
// ---------------------------------------------------------------------------
__global__ __launch_bounds__(256) void split_bf(
    const float* __restrict__ src, unsigned short* __restrict__ hi,
    unsigned short* __restrict__ lo, int n4)
{
    int i = blockIdx.x * 256 + threadIdx.x;
    if (i >= n4) return;
    float4 v = ((const float4*)src)[i];
    unsigned short h0 = f2bf_rne(v.x), h1 = f2bf_rne(v.y);
    unsigned short h2 = f2bf_rne(v.z), h3 = f2bf_rne(v.w);
    uint2 hv, lv;
    hv.x = (unsigned)h0 | ((unsigned)h1 << 16);
    hv.y = (unsigned)h2 | ((unsigned)h3 << 16);
    lv.x = (unsigned)f2bf_rne(v.x - bf2f(h0)) | ((unsigned)f2bf_rne(v.y - bf2f(h1)) << 16);
    lv.y = (unsigned)f2bf_rne(v.z - bf2f(h2)) | ((unsigned)f2bf_rne(v.w - bf2f(h3)) << 16);
    *(uint2*)(hi + (size_t)i * 4) = hv;
    *(uint2*)(lo + (size_t)i * 4) = lv;
}

// ---------------------------------------------------------------------------
// Split-bf16 MFMA GEMM mainloop (m97 structure), unchanged.
// ---------------------------------------------------------------------------
__device__ __forceinline__ void gemm_mainloop(
    const unsigned short* __restrict__ Ah, const unsigned short* __restrict__ Al,
    const unsigned short* __restrict__ Bh, const unsigned short* __restrict__ Bl,
    int n0, int m0, unsigned short* lds, f32x4 acc[4][4])
{
    const int t = threadIdx.x;
    const int lane = t & 63;
    const int wid = t >> 6;
    const int wn = wid & 1, wm = wid >> 1;
    const int quad = lane >> 4, n16 = lane & 15;

    unsigned short* lAh = lds;
    unsigned short* lAl = lds + 4096;
    unsigned short* lBh = lds + 8192;
    unsigned short* lBl = lds + 12288;

    int rowp[2], cp[2];
#pragma unroll
    for (int p = 0; p < 2; ++p) {
        int cidx = p * 256 + t;
        rowp[p] = cidx >> 2;
        cp[p]   = (cidx & 3) ^ ((rowp[p] >> 1) & 3);
    }
    const int wbase = (t >> 6) * 64;

    int offA[4], offB[4];
#pragma unroll
    for (int i = 0; i < 4; ++i) {
        int ra = wn * 64 + i * 16 + n16;
        offA[i] = ra * 32 + (quad ^ ((ra >> 1) & 3)) * 8;
        int rb = wm * 64 + i * 16 + n16;
        offB[i] = rb * 32 + (quad ^ ((rb >> 1) & 3)) * 8;
    }

    for (int k0 = 0; k0 < HIDDEN; k0 += 32) {
        __syncthreads();
#pragma unroll
        for (int p = 0; p < 2; ++p) {
            const size_t aoff = (size_t)(n0 + rowp[p]) * HIDDEN + k0 + cp[p] * 8;
            const size_t boff = (size_t)(m0 + rowp[p]) * HIDDEN + k0 + cp[p] * 8;
            const int ldst = (p * 256 + wbase) * 8;
            gl2lds16(Ah + aoff, lAh + ldst);
            gl2lds16(Al + aoff, lAl + ldst);
            gl2lds16(Bh + boff, lBh + ldst);
            gl2lds16(Bl + boff, lBl + ldst);
        }
        __syncthreads();

        bf16x8 fah[4], fal[4], fbh[4], fbl[4];
#pragma unroll
        for (int i = 0; i < 4; ++i) {
            fah[i] = *(const bf16x8*)(lAh + offA[i]);
            fal[i] = *(const bf16x8*)(lAl + offA[i]);
            fbh[i] = *(const bf16x8*)(lBh + offB[i]);
            fbl[i] = *(const bf16x8*)(lBl + offB[i]);
        }
#pragma unroll
        for (int i = 0; i < 4; ++i)
#pragma unroll
            for (int j = 0; j < 4; ++j) {
                acc[i][j] = __builtin_amdgcn_mfma_f32_16x16x32_bf16(fah[i], fbh[j], acc[i][j], 0, 0, 0);
                acc[i][j] = __builtin_amdgcn_mfma_f32_16x16x32_bf16(fah[i], fbl[j], acc[i][j], 0, 0, 0);
                acc[i][j] = __builtin_amdgcn_mfma_f32_16x16x32_bf16(fal[i], fbh[j], acc[i][j], 0, 0, 0);
            }
    }
}

// ---------------------------------------------------------------------------
// Fused QKV projection (unchanged).
// ---------------------------------------------------------------------------
__global__ __launch_bounds__(256) void qkv_gemm(
    const unsigned short* __restrict__ xh, const unsigned short* __restrict__ xl,
    const unsigned short* __restrict__ Wsp,
    unsigned short* __restrict__ Qh, unsigned short* __restrict__ Ql,
    unsigned short* __restrict__ Kh, unsigned short* __restrict__ Kl,
    unsigned short* __restrict__ Vt)
{
    __shared__ __align__(16) unsigned short lds[16384];
    const int z = blockIdx.z;
    const unsigned short* Wh = Wsp + (size_t)z * 2097152;
    const unsigned short* Wl = Wh + 1048576;
    const int m0 = blockIdx.x * 128, n0 = blockIdx.y * 128;

    f32x4 acc[4][4];
#pragma unroll
    for (int i = 0; i < 4; ++i)
#pragma unroll
        for (int j = 0; j < 4; ++j) acc[i][j] = (f32x4){0.f, 0.f, 0.f, 0.f};

    gemm_mainloop(Wh, Wl, xh, xl, n0, m0, lds, acc);

    const int t = threadIdx.x;
    const int lane = t & 63, wid = t >> 6;
    const int wn = wid & 1, wm = wid >> 1;
    const int quad = lane >> 4, n16 = lane & 15;
    const float scale = (z == 0) ? 0.125f : 1.0f;

    if (z < 2) {
        unsigned short* oh = z ? Kh : Qh;
        unsigned short* ol = z ? Kl : Ql;
#pragma unroll
        for (int i = 0; i < 4; ++i)
#pragma unroll
            for (int j = 0; j < 4; ++j) {
                int m  = m0 + wm * 64 + j * 16 + n16;
                int nn = n0 + wn * 64 + i * 16 + quad * 4;
                int bb = m >> 11, ss = m & (SEQ - 1);
                int hh = nn >> 6, dd = nn & 63;
                size_t base = ((size_t)(bb * HEADS + hh) * SEQ + ss) * HDIM + dd;
                unsigned short h[4], l[4];
#pragma unroll
                for (int r = 0; r < 4; ++r) {
                    float v = acc[i][j][r] * scale;
                    h[r] = f2bf_rne(v);
                    l[r] = f2bf_rne(v - bf2f(h[r]));
                }
                uint2 hv, lv;
                hv.x = (unsigned)h[0] | ((unsigned)h[1] << 16);
                hv.y = (unsigned)h[2] | ((unsigned)h[3] << 16);
                lv.x = (unsigned)l[0] | ((unsigned)l[1] << 16);
                lv.y = (unsigned)l[2] | ((unsigned)l[3] << 16);
                *(uint2*)(oh + base) = hv;
                *(uint2*)(ol + base) = lv;
            }
    } else {
#pragma unroll
        for (int i = 0; i < 4; ++i)
#pragma unroll
            for (int j = 0; j < 4; ++j) {
                int m  = m0 + wm * 64 + j * 16 + n16;
                int bb = m >> 11, ss = m & (SEQ - 1);
#pragma unroll
                for (int r = 0; r < 4; ++r) {
                    int nn = n0 + wn * 64 + i * 16 + quad * 4 + r;
                    int hh = nn >> 6, dd = nn & 63;
                    Vt[((size_t)(bb * HEADS + hh) * HDIM + dd) * SEQ + ss] =
                        f2bf_rne(acc[i][j][r]);
                }
            }
    }
}

// ---------------------------------------------------------------------------
// Final projection (unchanged).
// ---------------------------------------------------------------------------
__global__ __launch_bounds__(256) void out_gemm(
    const unsigned short* __restrict__ Oh, const unsigned short* __restrict__ Ol,
    const unsigned short* __restrict__ Woh, const unsigned short* __restrict__ Wol,
    const float* __restrict__ bias, float* __restrict__ out)
{
    __shared__ __align__(16) unsigned short lds[16384];
    const int m0 = blockIdx.x * 128, n0 = blockIdx.y * 128;

    f32x4 acc[4][4];
#pragma unroll
    for (int i = 0; i < 4; ++i)
#pragma unroll
        for (int j = 0; j < 4; ++j) acc[i][j] = (f32x4){0.f, 0.f, 0.f, 0.f};

    gemm_mainloop(Woh, Wol, Oh, Ol, n0, m0, lds, acc);

    const int t = threadIdx.x;
    const int lane = t & 63, wid = t >> 6;
    const int wn = wid & 1, wm = wid >> 1;
    const int quad = lane >> 4, n16 = lane & 15;
#pragma unroll
    for (int i = 0; i < 4; ++i)
#pragma unroll
        for (int j = 0; j < 4; ++j) {
            int m  = m0 + wm * 64 + j * 16 + n16;
            int nn = n0 + wn * 64 + i * 16 + quad * 4;
            float4 v;
            v.x = acc[i][j][0] + bias[nn + 0];
            v.y = acc[i][j][1] + bias[nn + 1];
            v.z = acc[i][j][2] + bias[nn + 2];
            v.w = acc[i][j][3] + bias[nn + 3];
            *(float4*)&out[(size_t)m * HIDDEN + nn] = v;
        }
}

// ---------------------------------------------------------------------------
// One 16-key QK^T score tile (split-bf16, 6 MFMAs). Deterministic: every call
// with the same inputs produces bitwise-identical scores, so the three passes
// below stay mutually consistent without storing the score matrix.
// ---------------------------------------------------------------------------
__device__ __forceinline__ f32x4 qk_tile(
    const unsigned short* __restrict__ khb, const unsigned short* __restrict__ klb,
    size_t kb, bf16x8 aqh0, bf16x8 aqh1, bf16x8 aql0, bf16x8 aql1)
{
    bf16x8 bh0 = *(const bf16x8*)(khb + kb);
    bf16x8 bh1 = *(const bf16x8*)(khb + kb + 32);
    bf16x8 bl0 = *(const bf16x8*)(klb + kb);
    bf16x8 bl1 = *(const bf16x8*)(klb + kb + 32);
    f32x4 a = {0.f, 0.f, 0.f, 0.f};
    a = __builtin_amdgcn_mfma_f32_16x16x32_bf16(aqh0, bh0, a, 0, 0, 0);
    a = __builtin_amdgcn_mfma_f32_16x16x32_bf16(aqh1, bh1, a, 0, 0, 0);
    a = __builtin_amdgcn_mfma_f32_16x16x32_bf16(aqh0, bl0, a, 0, 0, 0);
    a = __builtin_amdgcn_mfma_f32_16x16x32_bf16(aqh1, bl1, a, 0, 0, 0);
    a = __builtin_amdgcn_mfma_f32_16x16x32_bf16(aql0, bh0, a, 0, 0, 0);
    a = __builtin_amdgcn_mfma_f32_16x16x32_bf16(aql1, bh1, a, 0, 0, 0);
    return a;
}

// ---------------------------------------------------------------------------
// Fused adaptive sparse attention, RECOMPUTE edition.
// Scores are never stored: pass A (hist+max), pass B (candidate gather),
// pass C (softmax+PV) each recompute 16-key score tiles transiently.
// Register footprint ~90 -> no spill; LDS 44 KB -> 3 blocks/CU.
// ---------------------------------------------------------------------------
__global__ __launch_bounds__(256, 3) void attn_mfma(
    const unsigned short* __restrict__ Qh, const unsigned short* __restrict__ Ql,
    const unsigned short* __restrict__ Kh, const unsigned short* __restrict__ Kl,
    const unsigned short* __restrict__ Vt, const float* __restrict__ thrp,
    unsigned short* __restrict__ Oh, unsigned short* __restrict__ Ol)
{
    // U: hist[16][513] (32832 B) until scan done; then per-wave P[16][264] (8448 B/wave)
    __shared__ __align__(16) unsigned char U[33792];
    __shared__ __align__(16) float cand[16][64];
    __shared__ __align__(16) float Olds[16][64];
    __shared__ float smax[4][16], ssum[4][16];
    __shared__ unsigned csum[16][16];
    __shared__ float gmax[16], gsum[16], cutv[16];
    __shared__ int bcut[16], resid[16];
    __shared__ unsigned ccnt[16];

    const int t = threadIdx.x;
    const int lane = t & 63, wid = t >> 6;
    const int quad = lane >> 4, n16 = lane & 15;
    // XCD-local mapping: block i -> XCD i%8; all 128 q-blocks of one bh run
    // within one XCD window so its K (512 KB) + Vt (256 KB) stay L2-resident.
    const int bh = (blockIdx.x & 7) + 8 * (int)(blockIdx.x >> 10);
    const int q0 = ((blockIdx.x >> 3) & 127) * QT;
    const int row0 = quad * 4;

    unsigned* hist = (unsigned*)U;
    unsigned short* Pw = (unsigned short*)(U + wid * 8448);  // [16 rows][264 keys]

    const float thv = fminf(fmaxf(thrp[0], 0.f), 1.f);

    // zero LDS
    for (int j = t; j < 16*513; j += 256) hist[j] = 0u;
    for (int j = t; j < 16*64; j += 256) ((float*)Olds)[j] = 0.f;
    if (t < 16) ccnt[t] = 0u;
    __syncthreads();                         // #0: zeroed before pass-A atomics

    const size_t qoff = ((size_t)bh*SEQ + q0 + n16)*HDIM + quad*8;
    bf16x8 aqh0 = *(const bf16x8*)(Qh + qoff);
    bf16x8 aqh1 = *(const bf16x8*)(Qh + qoff + 32);
    bf16x8 aql0 = *(const bf16x8*)(Ql + qoff);
    bf16x8 aql1 = *(const bf16x8*)(Ql + qoff + 32);

    const unsigned short* khb = Kh + (size_t)bh*SEQ*HDIM;
    const unsigned short* klb = Kl + (size_t)bh*SEQ*HDIM;
    const size_t kb0 = ((size_t)(wid*512 + n16))*HDIM + quad*8;

    // ---------------- pass A: hist + rowmax (transient scores) ----------------
    float rmax[4] = {-1e30f, -1e30f, -1e30f, -1e30f};
#pragma unroll
    for (int tt = 0; tt < 32; ++tt) {
        f32x4 a = qk_tile(khb, klb, kb0 + (size_t)tt*16*HDIM, aqh0, aqh1, aql0, aql1);
#pragma unroll
        for (int r = 0; r < 4; ++r) {
            rmax[r] = fmaxf(rmax[r], a[r]);
            atomicAdd(&hist[(row0 + r)*513 + score_bucket(a[r])], 1u);
        }
    }
#pragma unroll
    for (int r = 0; r < 4; ++r) {
#pragma unroll
        for (int m = 1; m < 16; m <<= 1) rmax[r] = fmaxf(rmax[r], __shfl_xor(rmax[r], m));
    }
    if (n16 == 0) {
#pragma unroll
        for (int r = 0; r < 4; ++r) smax[wid][row0 + r] = rmax[r];
    }
    __syncthreads();                         // #1: hist + smax complete
    if (t < 16) gmax[t] = fmaxf(fmaxf(smax[0][t], smax[1][t]),
                                fmaxf(smax[2][t], smax[3][t]));

    // ---------------- chunk sums ----------------
    {
        int row = t >> 4, slot = t & 15;
        int btop = 512 - slot*32;
        unsigned s = 0;
        for (int b = btop - 32; b < btop; ++b) s += hist[row*513 + b];
        csum[row][slot] = s;
    }
    __syncthreads();                         // #2

    // ---------------- scan (register-resident, t<16) ----------------
    if (t < 16) {
        unsigned cs[16];
#pragma unroll
        for (int j = 0; j < 16; ++j) cs[j] = csum[t][j];
        unsigned cum = 0; int jc = -1;
#pragma unroll
        for (int j = 0; j < 16; ++j) {
            bool here = (jc < 0) && (cum + cs[j] >= (unsigned)KSEL);
            if (here) jc = j;
            if (jc < 0) cum += cs[j];
        }
        int btop = 512 - jc*32;
        unsigned hb[32];
#pragma unroll
        for (int i = 0; i < 32; ++i) hb[i] = hist[t*513 + btop - 1 - i];
        unsigned c2 = cum; int bsel = btop - 32; int rres = 1; bool found = false;
#pragma unroll
        for (int i = 0; i < 32; ++i) {
            bool here = !found && (c2 + hb[i] >= (unsigned)KSEL);
            if (here) { bsel = btop - 1 - i; rres = KSEL - (int)c2; found = true; }
            if (!found) c2 += hb[i];
        }
        bcut[t] = bsel; resid[t] = rres;
        cutv[t] = ((float)bsel - 256.0f) * 0.03125f;   // fallback: bucket lower edge
    }
    __syncthreads();                         // #3

    // ---------------- pass B: gather cutoff-bucket candidates (recompute) ------
    {
        int bc[4];
#pragma unroll
        for (int r = 0; r < 4; ++r) bc[r] = bcut[row0 + r];
#pragma unroll
        for (int tt = 0; tt < 32; ++tt) {
            f32x4 a = qk_tile(khb, klb, kb0 + (size_t)tt*16*HDIM, aqh0, aqh1, aql0, aql1);
#pragma unroll
            for (int r = 0; r < 4; ++r) {
                if (score_bucket(a[r]) == bc[r]) {
                    unsigned idx = atomicAdd(&ccnt[row0 + r], 1u);
                    if (idx < 64u) cand[row0 + r][idx] = a[r];
                }
            }
        }
    }
    __syncthreads();                         // #4

    // ---------------- exact rank among candidates ----------------
    {
        int row = t >> 4, slot = t & 15;
        int n = min((int)ccnt[row], 64);
        int r = resid[row];
        for (int i = slot; i < n; i += 16) {
            float c = cand[row][i];
            int gt = 0, ge = 0;
            for (int j = 0; j < n; ++j) {
                float x = cand[row][j];
                gt += (x > c); ge += (x >= c);
            }
            if (gt < r && ge >= r) cutv[row] = c;
        }
    }
    __syncthreads();                         // #5 (hist/cand dead; Pw region live)

    // ---------------- pass C: softmax + PV (recompute) ----------------
    float mrow[4], crow[4], l4[4];
#pragma unroll
    for (int r = 0; r < 4; ++r) {
        mrow[r] = gmax[row0 + r];
        crow[r] = fmaxf(cutv[row0 + r], thv);
        l4[r] = 0.f;
    }
    f32x4 oacc[4];
#pragma unroll
    for (int dt = 0; dt < 4; ++dt) oacc[dt] = (f32x4){0.f, 0.f, 0.f, 0.f};
    const unsigned short* vtb = Vt + (size_t)bh*HDIM*SEQ;

#pragma unroll
    for (int half = 0; half < 2; ++half) {
#pragma unroll
        for (int tt2 = 0; tt2 < 16; ++tt2) {
            int tt = half*16 + tt2;
            f32x4 a = qk_tile(khb, klb, kb0 + (size_t)tt*16*HDIM, aqh0, aqh1, aql0, aql1);
            int kl = tt2*16 + n16;
#pragma unroll
            for (int r = 0; r < 4; ++r) {
                float v = a[r];
                float p = (v >= crow[r]) ? __expf(v - mrow[r]) : 0.f;
                l4[r] += p;
                Pw[(row0 + r)*264 + kl] = f2bf_rne(p);
            }
        }
        // wave-private region; in-wave DS ordering makes writes visible to reads
#pragma unroll
        for (int kc = 0; kc < 8; ++kc) {
            bf16x8 af = *(const bf16x8*)(Pw + n16*264 + kc*32 + quad*8);
            const int sbase = wid*512 + half*256 + kc*32 + quad*8;
#pragma unroll
            for (int dt = 0; dt < 4; ++dt) {
                const size_t vb = ((size_t)(dt*16 + n16))*SEQ + sbase;
                bf16x8 bf = *(const bf16x8*)(vtb + vb);
                oacc[dt] = __builtin_amdgcn_mfma_f32_16x16x32_bf16(af, bf, oacc[dt], 0, 0, 0);
            }
        }
    }

    // ---------------- reductions + writeout ----------------
#pragma unroll
    for (int r = 0; r < 4; ++r) {
#pragma unroll
        for (int m = 1; m < 16; m <<= 1) l4[r] += __shfl_xor(l4[r], m);
    }
    if (n16 == 0) {
#pragma unroll
        for (int r = 0; r < 4; ++r) ssum[wid][row0 + r] = l4[r];
    }
#pragma unroll
    for (int dt = 0; dt < 4; ++dt)
#pragma unroll
        for (int r = 0; r < 4; ++r)
            atomicAdd(&Olds[row0 + r][dt*16 + n16], oacc[dt][r]);
    __syncthreads();                         // #6
    if (t < 16) gsum[t] = ssum[0][t] + ssum[1][t] + ssum[2][t] + ssum[3][t];
    __syncthreads();                         // #7
    {
        int row = t >> 4, d4 = (t & 15) * 4;
        float inv = 1.0f / gsum[row];
        float o0 = Olds[row][d4+0] * inv, o1 = Olds[row][d4+1] * inv;
        float o2 = Olds[row][d4+2] * inv, o3 = Olds[row][d4+3] * inv;
        unsigned short h0 = f2bf_rne(o0), h1 = f2bf_rne(o1);
        unsigned short h2 = f2bf_rne(o2), h3 = f2bf_rne(o3);
        uint2 hv, lv;
        hv.x = (unsigned)h0 | ((unsigned)h1 << 16);
        hv.y = (unsigned)h2 | ((unsigned)h3 << 16);
        lv.x = (unsigned)f2bf_rne(o0 - bf2f(h0)) | ((unsigned)f2bf_rne(o1 - bf2f(h1)) << 16);
        lv.y = (unsigned)f2bf_rne(o2 - bf2f(h2)) | ((unsigned)f2bf_rne(o3 - bf2f(h3)) << 16);
        const int bb = bh >> 4, hh = bh & 15;
        size_t base = ((size_t)(bb*SEQ + q0 + row))*HIDDEN + hh*HDIM + d4;
        *(uint2*)(Oh + base) = hv;
        *(uint2*)(Ol + base) = lv;
    }
}

// ---------------------------------------------------------------------------
extern "C" void kernel_launch(void* const* d_in, const int* in_sizes, int n_in,
                              void* d_out, int out_size, void* d_ws, size_t ws_size,
                              hipStream_t stream)
{
    (void)in_sizes; (void)n_in; (void)out_size; (void)ws_size;
    const float* x  = (const float*)d_in[0];
    const float* Wq = (const float*)d_in[1];
    const float* Wk = (const float*)d_in[2];
    const float* Wv = (const float*)d_in[3];
    const float* Wo = (const float*)d_in[4];
    const float* bo = (const float*)d_in[5];
    const float* at = (const float*)d_in[6];
    float* out = (float*)d_out;

    char* ws = (char*)d_ws;
    const size_t MB = 1048576;
    unsigned short* xh  = (unsigned short*)(ws);            // 8 MB; later Oh
    unsigned short* xl  = (unsigned short*)(ws + 8*MB);     // 8 MB; later Ol
    unsigned short* Wsp = (unsigned short*)(ws + 16*MB);    // 16 MB: 8 x 1M ushorts
    unsigned short* Qh  = (unsigned short*)(ws + 32*MB);
    unsigned short* Ql  = (unsigned short*)(ws + 40*MB);
    unsigned short* Kh  = (unsigned short*)(ws + 48*MB);
    unsigned short* Kl  = (unsigned short*)(ws + 56*MB);
    unsigned short* Vt  = (unsigned short*)d_out;           // front 8 MB of out (dead before out_gemm)

    split_bf<<<MTOT*HIDDEN/4/256, 256, 0, stream>>>(x,  xh, xl, MTOT*HIDDEN/4);
    split_bf<<<HIDDEN*HIDDEN/4/256, 256, 0, stream>>>(Wq, Wsp + 0u*1048576u, Wsp + 1u*1048576u, HIDDEN*HIDDEN/4);
    split_bf<<<HIDDEN*HIDDEN/4/256, 256, 0, stream>>>(Wk, Wsp + 2u*1048576u, Wsp + 3u*1048576u, HIDDEN*HIDDEN/4);
    split_bf<<<HIDDEN*HIDDEN/4/256, 256, 0, stream>>>(Wv, Wsp + 4u*1048576u, Wsp + 5u*1048576u, HIDDEN*HIDDEN/4);
    split_bf<<<HIDDEN*HIDDEN/4/256, 256, 0, stream>>>(Wo, Wsp + 6u*1048576u, Wsp + 7u*1048576u, HIDDEN*HIDDEN/4);

    qkv_gemm<<<dim3(MTOT/128, HIDDEN/128, 3), 256, 0, stream>>>(xh, xl, Wsp, Qh, Ql, Kh, Kl, Vt);
    attn_mfma<<<BATCH*HEADS*(SEQ/QT), 256, 0, stream>>>(Qh, Ql, Kh, Kl, Vt, at, xh, xl);
    out_gemm<<<dim3(MTOT/128, HIDDEN/128, 1), 256, 0, stream>>>(xh, xl, Wsp + 6u*1048576u, Wsp + 7u*1048576u, bo, out);
}

// Round 7
// 1225.715 us; speedup vs baseline: 1.0697x; 1.0697x over previous
//
#include <hip/hip_runtime.h>
#include <hip/hip_bf16.h>
#include <cstdint>
#include <cstddef>

#define HIDDEN 1024
#define HEADS  16
#define HDIM   64
#define BATCH  2
#define SEQ    2048
#define MTOT   (BATCH*SEQ)   // 4096 rows
#define KSEL   1024          // k_keep = S * (1 - 0.5)
#define QT     16            // q rows per attention block

typedef __attribute__((ext_vector_type(8))) short bf16x8;
typedef __attribute__((ext_vector_type(4))) float f32x4;

__device__ __forceinline__ unsigned short f2bf_rne(float f) {
    unsigned u = __float_as_uint(f);
    u += 0x7fffu + ((u >> 16) & 1u);
    return (unsigned short)(u >> 16);
}
__device__ __forceinline__ float bf2f(unsigned short h) {
    return __uint_as_float(((unsigned)h) << 16);
}
__device__ __forceinline__ int score_bucket(float v) {
    int b = (int)floorf(__fmaf_rn(v, 32.0f, 256.0f));
    return min(511, max(0, b));
}
__device__ __forceinline__ void gl2lds16(const unsigned short* g, unsigned short* l) {
    __builtin_amdgcn_global_load_lds(
        (const __attribute__((address_space(1))) unsigned int*)g,
        (__attribute__((address_space(3))) unsigned int*)l, 16, 0, 0);
}

// ---------------------------------------------------------------------------
// fp32 -> bf16 hi/lo split (memory-bound prep)
// ---------------------------------------------------------------------------
__global__ __launch_bounds__(256) void split_bf(
    const float* __restrict__ src, unsigned short* __restrict__ hi,
    unsigned short* __restrict__ lo, int n4)
{
    int i = blockIdx.x * 256 + threadIdx.x;
    if (i >= n4) return;
    float4 v = ((const float4*)src)[i];
    unsigned short h0 = f2bf_rne(v.x), h1 = f2bf_rne(v.y);
    unsigned short h2 = f2bf_rne(v.z), h3 = f2bf_rne(v.w);
    uint2 hv, lv;
    hv.x = (unsigned)h0 | ((unsigned)h1 << 16);
    hv.y = (unsigned)h2 | ((unsigned)h3 << 16);
    lv.x = (unsigned)f2bf_rne(v.x - bf2f(h0)) | ((unsigned)f2bf_rne(v.y - bf2f(h1)) << 16);
    lv.y = (unsigned)f2bf_rne(v.z - bf2f(h2)) | ((unsigned)f2bf_rne(v.w - bf2f(h3)) << 16);
    *(uint2*)(hi + (size_t)i * 4) = hv;
    *(uint2*)(lo + (size_t)i * 4) = lv;
}

// ---------------------------------------------------------------------------
// Split-bf16 MFMA GEMM mainloop (m97 structure), unchanged.
// ---------------------------------------------------------------------------
__device__ __forceinline__ void gemm_mainloop(
    const unsigned short* __restrict__ Ah, const unsigned short* __restrict__ Al,
    const unsigned short* __restrict__ Bh, const unsigned short* __restrict__ Bl,
    int n0, int m0, unsigned short* lds, f32x4 acc[4][4])
{
    const int t = threadIdx.x;
    const int lane = t & 63;
    const int wid = t >> 6;
    const int wn = wid & 1, wm = wid >> 1;
    const int quad = lane >> 4, n16 = lane & 15;

    unsigned short* lAh = lds;
    unsigned short* lAl = lds + 4096;
    unsigned short* lBh = lds + 8192;
    unsigned short* lBl = lds + 12288;

    int rowp[2], cp[2];
#pragma unroll
    for (int p = 0; p < 2; ++p) {
        int cidx = p * 256 + t;
        rowp[p] = cidx >> 2;
        cp[p]   = (cidx & 3) ^ ((rowp[p] >> 1) & 3);
    }
    const int wbase = (t >> 6) * 64;

    int offA[4], offB[4];
#pragma unroll
    for (int i = 0; i < 4; ++i) {
        int ra = wn * 64 + i * 16 + n16;
        offA[i] = ra * 32 + (quad ^ ((ra >> 1) & 3)) * 8;
        int rb = wm * 64 + i * 16 + n16;
        offB[i] = rb * 32 + (quad ^ ((rb >> 1) & 3)) * 8;
    }

    for (int k0 = 0; k0 < HIDDEN; k0 += 32) {
        __syncthreads();
#pragma unroll
        for (int p = 0; p < 2; ++p) {
            const size_t aoff = (size_t)(n0 + rowp[p]) * HIDDEN + k0 + cp[p] * 8;
            const size_t boff = (size_t)(m0 + rowp[p]) * HIDDEN + k0 + cp[p] * 8;
            const int ldst = (p * 256 + wbase) * 8;
            gl2lds16(Ah + aoff, lAh + ldst);
            gl2lds16(Al + aoff, lAl + ldst);
            gl2lds16(Bh + boff, lBh + ldst);
            gl2lds16(Bl + boff, lBl + ldst);
        }
        __syncthreads();

        bf16x8 fah[4], fal[4], fbh[4], fbl[4];
#pragma unroll
        for (int i = 0; i < 4; ++i) {
            fah[i] = *(const bf16x8*)(lAh + offA[i]);
            fal[i] = *(const bf16x8*)(lAl + offA[i]);
            fbh[i] = *(const bf16x8*)(lBh + offB[i]);
            fbl[i] = *(const bf16x8*)(lBl + offB[i]);
        }
#pragma unroll
        for (int i = 0; i < 4; ++i)
#pragma unroll
            for (int j = 0; j < 4; ++j) {
                acc[i][j] = __builtin_amdgcn_mfma_f32_16x16x32_bf16(fah[i], fbh[j], acc[i][j], 0, 0, 0);
                acc[i][j] = __builtin_amdgcn_mfma_f32_16x16x32_bf16(fah[i], fbl[j], acc[i][j], 0, 0, 0);
                acc[i][j] = __builtin_amdgcn_mfma_f32_16x16x32_bf16(fal[i], fbh[j], acc[i][j], 0, 0, 0);
            }
    }
}

// ---------------------------------------------------------------------------
// Fused QKV projection (unchanged).
// ---------------------------------------------------------------------------
__global__ __launch_bounds__(256) void qkv_gemm(
    const unsigned short* __restrict__ xh, const unsigned short* __restrict__ xl,
    const unsigned short* __restrict__ Wsp,
    unsigned short* __restrict__ Qh, unsigned short* __restrict__ Ql,
    unsigned short* __restrict__ Kh, unsigned short* __restrict__ Kl,
    unsigned short* __restrict__ Vt)
{
    __shared__ __align__(16) unsigned short lds[16384];
    const int z = blockIdx.z;
    const unsigned short* Wh = Wsp + (size_t)z * 2097152;
    const unsigned short* Wl = Wh + 1048576;
    const int m0 = blockIdx.x * 128, n0 = blockIdx.y * 128;

    f32x4 acc[4][4];
#pragma unroll
    for (int i = 0; i < 4; ++i)
#pragma unroll
        for (int j = 0; j < 4; ++j) acc[i][j] = (f32x4){0.f, 0.f, 0.f, 0.f};

    gemm_mainloop(Wh, Wl, xh, xl, n0, m0, lds, acc);

    const int t = threadIdx.x;
    const int lane = t & 63, wid = t >> 6;
    const int wn = wid & 1, wm = wid >> 1;
    const int quad = lane >> 4, n16 = lane & 15;
    const float scale = (z == 0) ? 0.125f : 1.0f;

    if (z < 2) {
        unsigned short* oh = z ? Kh : Qh;
        unsigned short* ol = z ? Kl : Ql;
#pragma unroll
        for (int i = 0; i < 4; ++i)
#pragma unroll
            for (int j = 0; j < 4; ++j) {
                int m  = m0 + wm * 64 + j * 16 + n16;
                int nn = n0 + wn * 64 + i * 16 + quad * 4;
                int bb = m >> 11, ss = m & (SEQ - 1);
                int hh = nn >> 6, dd = nn & 63;
                size_t base = ((size_t)(bb * HEADS + hh) * SEQ + ss) * HDIM + dd;
                unsigned short h[4], l[4];
#pragma unroll
                for (int r = 0; r < 4; ++r) {
                    float v = acc[i][j][r] * scale;
                    h[r] = f2bf_rne(v);
                    l[r] = f2bf_rne(v - bf2f(h[r]));
                }
                uint2 hv, lv;
                hv.x = (unsigned)h[0] | ((unsigned)h[1] << 16);
                hv.y = (unsigned)h[2] | ((unsigned)h[3] << 16);
                lv.x = (unsigned)l[0] | ((unsigned)l[1] << 16);
                lv.y = (unsigned)l[2] | ((unsigned)l[3] << 16);
                *(uint2*)(oh + base) = hv;
                *(uint2*)(ol + base) = lv;
            }
    } else {
#pragma unroll
        for (int i = 0; i < 4; ++i)
#pragma unroll
            for (int j = 0; j < 4; ++j) {
                int m  = m0 + wm * 64 + j * 16 + n16;
                int bb = m >> 11, ss = m & (SEQ - 1);
#pragma unroll
                for (int r = 0; r < 4; ++r) {
                    int nn = n0 + wn * 64 + i * 16 + quad * 4 + r;
                    int hh = nn >> 6, dd = nn & 63;
                    Vt[((size_t)(bb * HEADS + hh) * HDIM + dd) * SEQ + ss] =
                        f2bf_rne(acc[i][j][r]);
                }
            }
    }
}

// ---------------------------------------------------------------------------
// Final projection (unchanged).
// ---------------------------------------------------------------------------
__global__ __launch_bounds__(256) void out_gemm(
    const unsigned short* __restrict__ Oh, const unsigned short* __restrict__ Ol,
    const unsigned short* __restrict__ Woh, const unsigned short* __restrict__ Wol,
    const float* __restrict__ bias, float* __restrict__ out)
{
    __shared__ __align__(16) unsigned short lds[16384];
    const int m0 = blockIdx.x * 128, n0 = blockIdx.y * 128;

    f32x4 acc[4][4];
#pragma unroll
    for (int i = 0; i < 4; ++i)
#pragma unroll
        for (int j = 0; j < 4; ++j) acc[i][j] = (f32x4){0.f, 0.f, 0.f, 0.f};

    gemm_mainloop(Woh, Wol, Oh, Ol, n0, m0, lds, acc);

    const int t = threadIdx.x;
    const int lane = t & 63, wid = t >> 6;
    const int wn = wid & 1, wm = wid >> 1;
    const int quad = lane >> 4, n16 = lane & 15;
#pragma unroll
    for (int i = 0; i < 4; ++i)
#pragma unroll
        for (int j = 0; j < 4; ++j) {
            int m  = m0 + wm * 64 + j * 16 + n16;
            int nn = n0 + wn * 64 + i * 16 + quad * 4;
            float4 v;
            v.x = acc[i][j][0] + bias[nn + 0];
            v.y = acc[i][j][1] + bias[nn + 1];
            v.z = acc[i][j][2] + bias[nn + 2];
            v.w = acc[i][j][3] + bias[nn + 3];
            *(float4*)&out[(size_t)m * HIDDEN + nn] = v;
        }
}

// ---------------------------------------------------------------------------
// One 16-key QK^T score tile (split-bf16, 6 MFMAs). Deterministic -> the three
// passes below stay mutually consistent without storing the score matrix.
// ---------------------------------------------------------------------------
__device__ __forceinline__ f32x4 qk_tile(
    const unsigned short* __restrict__ khb, const unsigned short* __restrict__ klb,
    size_t kb, bf16x8 aqh0, bf16x8 aqh1, bf16x8 aql0, bf16x8 aql1)
{
    bf16x8 bh0 = *(const bf16x8*)(khb + kb);
    bf16x8 bh1 = *(const bf16x8*)(khb + kb + 32);
    bf16x8 bl0 = *(const bf16x8*)(klb + kb);
    bf16x8 bl1 = *(const bf16x8*)(klb + kb + 32);
    f32x4 a = {0.f, 0.f, 0.f, 0.f};
    a = __builtin_amdgcn_mfma_f32_16x16x32_bf16(aqh0, bh0, a, 0, 0, 0);
    a = __builtin_amdgcn_mfma_f32_16x16x32_bf16(aqh1, bh1, a, 0, 0, 0);
    a = __builtin_amdgcn_mfma_f32_16x16x32_bf16(aqh0, bl0, a, 0, 0, 0);
    a = __builtin_amdgcn_mfma_f32_16x16x32_bf16(aqh1, bl1, a, 0, 0, 0);
    a = __builtin_amdgcn_mfma_f32_16x16x32_bf16(aql0, bh0, a, 0, 0, 0);
    a = __builtin_amdgcn_mfma_f32_16x16x32_bf16(aql1, bh1, a, 0, 0, 0);
    return a;
}

// ---------------------------------------------------------------------------
// Fused adaptive sparse attention, RECOMPUTE + BOUNDED-UNROLL edition.
// Rounds 2-6 all spilled because full `#pragma unroll` over 32 key-tiles let
// the compiler hoist up to 128 K-tile loads (512 VGPRs wanted) -> scratch.
// `#pragma unroll 2` bounds the hoisted live set to ~2 tiles (~40 regs);
// total ~120 regs fits (256,3)'s ~170 budget -> 3 blocks/CU, zero spill.
// ---------------------------------------------------------------------------
__global__ __launch_bounds__(256, 3) void attn_mfma(
    const unsigned short* __restrict__ Qh, const unsigned short* __restrict__ Ql,
    const unsigned short* __restrict__ Kh, const unsigned short* __restrict__ Kl,
    const unsigned short* __restrict__ Vt, const float* __restrict__ thrp,
    unsigned short* __restrict__ Oh, unsigned short* __restrict__ Ol)
{
    // U: hist[16][513] (32832 B) until scan done; then per-wave P[16][264] (8448 B/wave)
    __shared__ __align__(16) unsigned char U[33792];
    __shared__ __align__(16) float cand[16][64];
    __shared__ __align__(16) float Olds[16][64];
    __shared__ float smax[4][16], ssum[4][16];
    __shared__ unsigned csum[16][16];
    __shared__ float gmax[16], gsum[16], cutv[16];
    __shared__ int bcut[16], resid[16];
    __shared__ unsigned ccnt[16];

    const int t = threadIdx.x;
    const int lane = t & 63, wid = t >> 6;
    const int quad = lane >> 4, n16 = lane & 15;
    // XCD-local mapping: block i -> XCD i%8; all 128 q-blocks of one bh run
    // within one XCD window so its K (512 KB) + Vt (256 KB) stay L2-resident.
    const int bh = (blockIdx.x & 7) + 8 * (int)(blockIdx.x >> 10);
    const int q0 = ((blockIdx.x >> 3) & 127) * QT;
    const int row0 = quad * 4;

    unsigned* hist = (unsigned*)U;
    unsigned short* Pw = (unsigned short*)(U + wid * 8448);  // [16 rows][264 keys]

    const float thv = fminf(fmaxf(thrp[0], 0.f), 1.f);

    // zero LDS
    for (int j = t; j < 16*513; j += 256) hist[j] = 0u;
    for (int j = t; j < 16*64; j += 256) ((float*)Olds)[j] = 0.f;
    if (t < 16) ccnt[t] = 0u;
    __syncthreads();                         // #0: zeroed before pass-A atomics

    const size_t qoff = ((size_t)bh*SEQ + q0 + n16)*HDIM + quad*8;
    bf16x8 aqh0 = *(const bf16x8*)(Qh + qoff);
    bf16x8 aqh1 = *(const bf16x8*)(Qh + qoff + 32);
    bf16x8 aql0 = *(const bf16x8*)(Ql + qoff);
    bf16x8 aql1 = *(const bf16x8*)(Ql + qoff + 32);

    const unsigned short* khb = Kh + (size_t)bh*SEQ*HDIM;
    const unsigned short* klb = Kl + (size_t)bh*SEQ*HDIM;
    const size_t kb0 = ((size_t)(wid*512 + n16))*HDIM + quad*8;

    // ---------------- pass A: hist + rowmax (transient scores) ----------------
    float rmax[4] = {-1e30f, -1e30f, -1e30f, -1e30f};
#pragma unroll 2
    for (int tt = 0; tt < 32; ++tt) {
        f32x4 a = qk_tile(khb, klb, kb0 + (size_t)tt*16*HDIM, aqh0, aqh1, aql0, aql1);
#pragma unroll
        for (int r = 0; r < 4; ++r) {
            rmax[r] = fmaxf(rmax[r], a[r]);
            atomicAdd(&hist[(row0 + r)*513 + score_bucket(a[r])], 1u);
        }
    }
#pragma unroll
    for (int r = 0; r < 4; ++r) {
#pragma unroll
        for (int m = 1; m < 16; m <<= 1) rmax[r] = fmaxf(rmax[r], __shfl_xor(rmax[r], m));
    }
    if (n16 == 0) {
#pragma unroll
        for (int r = 0; r < 4; ++r) smax[wid][row0 + r] = rmax[r];
    }
    __syncthreads();                         // #1: hist + smax complete
    if (t < 16) gmax[t] = fmaxf(fmaxf(smax[0][t], smax[1][t]),
                                fmaxf(smax[2][t], smax[3][t]));

    // ---------------- chunk sums ----------------
    {
        int row = t >> 4, slot = t & 15;
        int btop = 512 - slot*32;
        unsigned s = 0;
        for (int b = btop - 32; b < btop; ++b) s += hist[row*513 + b];
        csum[row][slot] = s;
    }
    __syncthreads();                         // #2

    // ---------------- scan (register-resident, t<16) ----------------
    if (t < 16) {
        unsigned cs[16];
#pragma unroll
        for (int j = 0; j < 16; ++j) cs[j] = csum[t][j];
        unsigned cum = 0; int jc = -1;
#pragma unroll
        for (int j = 0; j < 16; ++j) {
            bool here = (jc < 0) && (cum + cs[j] >= (unsigned)KSEL);
            if (here) jc = j;
            if (jc < 0) cum += cs[j];
        }
        int btop = 512 - jc*32;
        unsigned hb[32];
#pragma unroll 4
        for (int i = 0; i < 32; ++i) hb[i] = hist[t*513 + btop - 1 - i];
        unsigned c2 = cum; int bsel = btop - 32; int rres = 1; bool found = false;
#pragma unroll
        for (int i = 0; i < 32; ++i) {
            bool here = !found && (c2 + hb[i] >= (unsigned)KSEL);
            if (here) { bsel = btop - 1 - i; rres = KSEL - (int)c2; found = true; }
            if (!found) c2 += hb[i];
        }
        bcut[t] = bsel; resid[t] = rres;
        cutv[t] = ((float)bsel - 256.0f) * 0.03125f;   // fallback: bucket lower edge
    }
    __syncthreads();                         // #3

    // ---------------- pass B: gather cutoff-bucket candidates (recompute) ------
    {
        int bc[4];
#pragma unroll
        for (int r = 0; r < 4; ++r) bc[r] = bcut[row0 + r];
#pragma unroll 2
        for (int tt = 0; tt < 32; ++tt) {
            f32x4 a = qk_tile(khb, klb, kb0 + (size_t)tt*16*HDIM, aqh0, aqh1, aql0, aql1);
#pragma unroll
            for (int r = 0; r < 4; ++r) {
                if (score_bucket(a[r]) == bc[r]) {
                    unsigned idx = atomicAdd(&ccnt[row0 + r], 1u);
                    if (idx < 64u) cand[row0 + r][idx] = a[r];
                }
            }
        }
    }
    __syncthreads();                         // #4

    // ---------------- exact rank among candidates ----------------
    {
        int row = t >> 4, slot = t & 15;
        int n = min((int)ccnt[row], 64);
        int r = resid[row];
        for (int i = slot; i < n; i += 16) {
            float c = cand[row][i];
            int gt = 0, ge = 0;
            for (int j = 0; j < n; ++j) {
                float x = cand[row][j];
                gt += (x > c); ge += (x >= c);
            }
            if (gt < r && ge >= r) cutv[row] = c;
        }
    }
    __syncthreads();                         // #5 (hist/cand dead; Pw region live)

    // ---------------- pass C: softmax + PV (recompute) ----------------
    float mrow[4], crow[4], l4[4];
#pragma unroll
    for (int r = 0; r < 4; ++r) {
        mrow[r] = gmax[row0 + r];
        crow[r] = fmaxf(cutv[row0 + r], thv);
        l4[r] = 0.f;
    }
    f32x4 oacc[4];
#pragma unroll
    for (int dt = 0; dt < 4; ++dt) oacc[dt] = (f32x4){0.f, 0.f, 0.f, 0.f};
    const unsigned short* vtb = Vt + (size_t)bh*HDIM*SEQ;

    for (int half = 0; half < 2; ++half) {
#pragma unroll 2
        for (int tt2 = 0; tt2 < 16; ++tt2) {
            int tt = half*16 + tt2;
            f32x4 a = qk_tile(khb, klb, kb0 + (size_t)tt*16*HDIM, aqh0, aqh1, aql0, aql1);
            int kl = tt2*16 + n16;
#pragma unroll
            for (int r = 0; r < 4; ++r) {
                float v = a[r];
                float p = (v >= crow[r]) ? __expf(v - mrow[r]) : 0.f;
                l4[r] += p;
                Pw[(row0 + r)*264 + kl] = f2bf_rne(p);
            }
        }
        // wave-private region; in-wave DS ordering makes writes visible to reads
#pragma unroll 2
        for (int kc = 0; kc < 8; ++kc) {
            bf16x8 af = *(const bf16x8*)(Pw + n16*264 + kc*32 + quad*8);
            const int sbase = wid*512 + half*256 + kc*32 + quad*8;
#pragma unroll
            for (int dt = 0; dt < 4; ++dt) {
                const size_t vb = ((size_t)(dt*16 + n16))*SEQ + sbase;
                bf16x8 bf = *(const bf16x8*)(vtb + vb);
                oacc[dt] = __builtin_amdgcn_mfma_f32_16x16x32_bf16(af, bf, oacc[dt], 0, 0, 0);
            }
        }
    }

    // ---------------- reductions + writeout ----------------
#pragma unroll
    for (int r = 0; r < 4; ++r) {
#pragma unroll
        for (int m = 1; m < 16; m <<= 1) l4[r] += __shfl_xor(l4[r], m);
    }
    if (n16 == 0) {
#pragma unroll
        for (int r = 0; r < 4; ++r) ssum[wid][row0 + r] = l4[r];
    }
#pragma unroll
    for (int dt = 0; dt < 4; ++dt)
#pragma unroll
        for (int r = 0; r < 4; ++r)
            atomicAdd(&Olds[row0 + r][dt*16 + n16], oacc[dt][r]);
    __syncthreads();                         // #6
    if (t < 16) gsum[t] = ssum[0][t] + ssum[1][t] + ssum[2][t] + ssum[3][t];
    __syncthreads();                         // #7
    {
        int row = t >> 4, d4 = (t & 15) * 4;
        float inv = 1.0f / gsum[row];
        float o0 = Olds[row][d4+0] * inv, o1 = Olds[row][d4+1] * inv;
        float o2 = Olds[row][d4+2] * inv, o3 = Olds[row][d4+3] * inv;
        unsigned short h0 = f2bf_rne(o0), h1 = f2bf_rne(o1);
        unsigned short h2 = f2bf_rne(o2), h3 = f2bf_rne(o3);
        uint2 hv, lv;
        hv.x = (unsigned)h0 | ((unsigned)h1 << 16);
        hv.y = (unsigned)h2 | ((unsigned)h3 << 16);
        lv.x = (unsigned)f2bf_rne(o0 - bf2f(h0)) | ((unsigned)f2bf_rne(o1 - bf2f(h1)) << 16);
        lv.y = (unsigned)f2bf_rne(o2 - bf2f(h2)) | ((unsigned)f2bf_rne(o3 - bf2f(h3)) << 16);
        const int bb = bh >> 4, hh = bh & 15;
        size_t base = ((size_t)(bb*SEQ + q0 + row))*HIDDEN + hh*HDIM + d4;
        *(uint2*)(Oh + base) = hv;
        *(uint2*)(Ol + base) = lv;
    }
}

// ---------------------------------------------------------------------------
extern "C" void kernel_launch(void* const* d_in, const int* in_sizes, int n_in,
                              void* d_out, int out_size, void* d_ws, size_t ws_size,
                              hipStream_t stream)
{
    (void)in_sizes; (void)n_in; (void)out_size; (void)ws_size;
    const float* x  = (const float*)d_in[0];
    const float* Wq = (const float*)d_in[1];
    const float* Wk = (const float*)d_in[2];
    const float* Wv = (const float*)d_in[3];
    const float* Wo = (const float*)d_in[4];
    const float* bo = (const float*)d_in[5];
    const float* at = (const float*)d_in[6];
    float* out = (float*)d_out;

    char* ws = (char*)d_ws;
    const size_t MB = 1048576;
    unsigned short* xh  = (unsigned short*)(ws);            // 8 MB; later Oh
    unsigned short* xl  = (unsigned short*)(ws + 8*MB);     // 8 MB; later Ol
    unsigned short* Wsp = (unsigned short*)(ws + 16*MB);    // 16 MB: 8 x 1M ushorts
    unsigned short* Qh  = (unsigned short*)(ws + 32*MB);
    unsigned short* Ql  = (unsigned short*)(ws + 40*MB);
    unsigned short* Kh  = (unsigned short*)(ws + 48*MB);
    unsigned short* Kl  = (unsigned short*)(ws + 56*MB);
    unsigned short* Vt  = (unsigned short*)d_out;           // front 8 MB of out (dead before out_gemm)

    split_bf<<<MTOT*HIDDEN/4/256, 256, 0, stream>>>(x,  xh, xl, MTOT*HIDDEN/4);
    split_bf<<<HIDDEN*HIDDEN/4/256, 256, 0, stream>>>(Wq, Wsp + 0u*1048576u, Wsp + 1u*1048576u, HIDDEN*HIDDEN/4);
    split_bf<<<HIDDEN*HIDDEN/4/256, 256, 0, stream>>>(Wk, Wsp + 2u*1048576u, Wsp + 3u*1048576u, HIDDEN*HIDDEN/4);
    split_bf<<<HIDDEN*HIDDEN/4/256, 256, 0, stream>>>(Wv, Wsp + 4u*1048576u, Wsp + 5u*1048576u, HIDDEN*HIDDEN/4);
    split_bf<<<HIDDEN*HIDDEN/4/256, 256, 0, stream>>>(Wo, Wsp + 6u*1048576u, Wsp + 7u*1048576u, HIDDEN*HIDDEN/4);

    qkv_gemm<<<dim3(MTOT/128, HIDDEN/128, 3), 256, 0, stream>>>(xh, xl, Wsp, Qh, Ql, Kh, Kl, Vt);
    attn_mfma<<<BATCH*HEADS*(SEQ/QT), 256, 0, stream>>>(Qh, Ql, Kh, Kl, Vt, at, xh, xl);
    out_gemm<<<dim3(MTOT/128, HIDDEN/128, 1), 256, 0, stream>>>(xh, xl, Wsp + 6u*1048576u, Wsp + 7u*1048576u, bo, out);
}

// Round 8
// 765.568 us; speedup vs baseline: 1.7126x; 1.6011x over previous
//
#include <hip/hip_runtime.h>
#include <hip/hip_bf16.h>
#include <cstdint>
#include <cstddef>

#define HIDDEN 1024
#define HEADS  16
#define HDIM   64
#define BATCH  2
#define SEQ    2048
#define MTOT   (BATCH*SEQ)   // 4096 rows
#define KSEL   1024          // k_keep = S * (1 - 0.5)
#define QT     16            // q rows per attention block

typedef __attribute__((ext_vector_type(8))) short bf16x8;
typedef __attribute__((ext_vector_type(4))) float f32x4;

__device__ __forceinline__ unsigned short f2bf_rne(float f) {
    unsigned u = __float_as_uint(f);
    u += 0x7fffu + ((u >> 16) & 1u);
    return (unsigned short)(u >> 16);
}
__device__ __forceinline__ float bf2f(unsigned short h) {
    return __uint_as_float(((unsigned)h) << 16);
}
__device__ __forceinline__ int score_bucket(float v) {
    int b = (int)floorf(__fmaf_rn(v, 32.0f, 256.0f));
    return min(511, max(0, b));
}
__device__ __forceinline__ void gl2lds16(const unsigned short* g, unsigned short* l) {
    __builtin_amdgcn_global_load_lds(
        (const __attribute__((address_space(1))) unsigned int*)g,
        (__attribute__((address_space(3))) unsigned int*)l, 16, 0, 0);
}

// ---------------------------------------------------------------------------
// fp32 -> bf16 hi/lo split (memory-bound prep)
// ---------------------------------------------------------------------------
__global__ __launch_bounds__(256) void split_bf(
    const float* __restrict__ src, unsigned short* __restrict__ hi,
    unsigned short* __restrict__ lo, int n4)
{
    int i = blockIdx.x * 256 + threadIdx.x;
    if (i >= n4) return;
    float4 v = ((const float4*)src)[i];
    unsigned short h0 = f2bf_rne(v.x), h1 = f2bf_rne(v.y);
    unsigned short h2 = f2bf_rne(v.z), h3 = f2bf_rne(v.w);
    uint2 hv, lv;
    hv.x = (unsigned)h0 | ((unsigned)h1 << 16);
    hv.y = (unsigned)h2 | ((unsigned)h3 << 16);
    lv.x = (unsigned)f2bf_rne(v.x - bf2f(h0)) | ((unsigned)f2bf_rne(v.y - bf2f(h1)) << 16);
    lv.y = (unsigned)f2bf_rne(v.z - bf2f(h2)) | ((unsigned)f2bf_rne(v.w - bf2f(h3)) << 16);
    *(uint2*)(hi + (size_t)i * 4) = hv;
    *(uint2*)(lo + (size_t)i * 4) = lv;
}

// ---------------------------------------------------------------------------
// Split-bf16 MFMA GEMM mainloop (m97 structure), unchanged.
// ---------------------------------------------------------------------------
__device__ __forceinline__ void gemm_mainloop(
    const unsigned short* __restrict__ Ah, const unsigned short* __restrict__ Al,
    const unsigned short* __restrict__ Bh, const unsigned short* __restrict__ Bl,
    int n0, int m0, unsigned short* lds, f32x4 acc[4][4])
{
    const int t = threadIdx.x;
    const int lane = t & 63;
    const int wid = t >> 6;
    const int wn = wid & 1, wm = wid >> 1;
    const int quad = lane >> 4, n16 = lane & 15;

    unsigned short* lAh = lds;
    unsigned short* lAl = lds + 4096;
    unsigned short* lBh = lds + 8192;
    unsigned short* lBl = lds + 12288;

    int rowp[2], cp[2];
#pragma unroll
    for (int p = 0; p < 2; ++p) {
        int cidx = p * 256 + t;
        rowp[p] = cidx >> 2;
        cp[p]   = (cidx & 3) ^ ((rowp[p] >> 1) & 3);
    }
    const int wbase = (t >> 6) * 64;

    int offA[4], offB[4];
#pragma unroll
    for (int i = 0; i < 4; ++i) {
        int ra = wn * 64 + i * 16 + n16;
        offA[i] = ra * 32 + (quad ^ ((ra >> 1) & 3)) * 8;
        int rb = wm * 64 + i * 16 + n16;
        offB[i] = rb * 32 + (quad ^ ((rb >> 1) & 3)) * 8;
    }

    for (int k0 = 0; k0 < HIDDEN; k0 += 32) {
        __syncthreads();
#pragma unroll
        for (int p = 0; p < 2; ++p) {
            const size_t aoff = (size_t)(n0 + rowp[p]) * HIDDEN + k0 + cp[p] * 8;
            const size_t boff = (size_t)(m0 + rowp[p]) * HIDDEN + k0 + cp[p] * 8;
            const int ldst = (p * 256 + wbase) * 8;
            gl2lds16(Ah + aoff, lAh + ldst);
            gl2lds16(Al + aoff, lAl + ldst);
            gl2lds16(Bh + boff, lBh + ldst);
            gl2lds16(Bl + boff, lBl + ldst);
        }
        __syncthreads();

        bf16x8 fah[4], fal[4], fbh[4], fbl[4];
#pragma unroll
        for (int i = 0; i < 4; ++i) {
            fah[i] = *(const bf16x8*)(lAh + offA[i]);
            fal[i] = *(const bf16x8*)(lAl + offA[i]);
            fbh[i] = *(const bf16x8*)(lBh + offB[i]);
            fbl[i] = *(const bf16x8*)(lBl + offB[i]);
        }
#pragma unroll
        for (int i = 0; i < 4; ++i)
#pragma unroll
            for (int j = 0; j < 4; ++j) {
                acc[i][j] = __builtin_amdgcn_mfma_f32_16x16x32_bf16(fah[i], fbh[j], acc[i][j], 0, 0, 0);
                acc[i][j] = __builtin_amdgcn_mfma_f32_16x16x32_bf16(fah[i], fbl[j], acc[i][j], 0, 0, 0);
                acc[i][j] = __builtin_amdgcn_mfma_f32_16x16x32_bf16(fal[i], fbh[j], acc[i][j], 0, 0, 0);
            }
    }
}

// ---------------------------------------------------------------------------
// Fused QKV projection (unchanged).
// ---------------------------------------------------------------------------
__global__ __launch_bounds__(256) void qkv_gemm(
    const unsigned short* __restrict__ xh, const unsigned short* __restrict__ xl,
    const unsigned short* __restrict__ Wsp,
    unsigned short* __restrict__ Qh, unsigned short* __restrict__ Ql,
    unsigned short* __restrict__ Kh, unsigned short* __restrict__ Kl,
    unsigned short* __restrict__ Vt)
{
    __shared__ __align__(16) unsigned short lds[16384];
    const int z = blockIdx.z;
    const unsigned short* Wh = Wsp + (size_t)z * 2097152;
    const unsigned short* Wl = Wh + 1048576;
    const int m0 = blockIdx.x * 128, n0 = blockIdx.y * 128;

    f32x4 acc[4][4];
#pragma unroll
    for (int i = 0; i < 4; ++i)
#pragma unroll
        for (int j = 0; j < 4; ++j) acc[i][j] = (f32x4){0.f, 0.f, 0.f, 0.f};

    gemm_mainloop(Wh, Wl, xh, xl, n0, m0, lds, acc);

    const int t = threadIdx.x;
    const int lane = t & 63, wid = t >> 6;
    const int wn = wid & 1, wm = wid >> 1;
    const int quad = lane >> 4, n16 = lane & 15;
    const float scale = (z == 0) ? 0.125f : 1.0f;

    if (z < 2) {
        unsigned short* oh = z ? Kh : Qh;
        unsigned short* ol = z ? Kl : Ql;
#pragma unroll
        for (int i = 0; i < 4; ++i)
#pragma unroll
            for (int j = 0; j < 4; ++j) {
                int m  = m0 + wm * 64 + j * 16 + n16;
                int nn = n0 + wn * 64 + i * 16 + quad * 4;
                int bb = m >> 11, ss = m & (SEQ - 1);
                int hh = nn >> 6, dd = nn & 63;
                size_t base = ((size_t)(bb * HEADS + hh) * SEQ + ss) * HDIM + dd;
                unsigned short h[4], l[4];
#pragma unroll
                for (int r = 0; r < 4; ++r) {
                    float v = acc[i][j][r] * scale;
                    h[r] = f2bf_rne(v);
                    l[r] = f2bf_rne(v - bf2f(h[r]));
                }
                uint2 hv, lv;
                hv.x = (unsigned)h[0] | ((unsigned)h[1] << 16);
                hv.y = (unsigned)h[2] | ((unsigned)h[3] << 16);
                lv.x = (unsigned)l[0] | ((unsigned)l[1] << 16);
                lv.y = (unsigned)l[2] | ((unsigned)l[3] << 16);
                *(uint2*)(oh + base) = hv;
                *(uint2*)(ol + base) = lv;
            }
    } else {
#pragma unroll
        for (int i = 0; i < 4; ++i)
#pragma unroll
            for (int j = 0; j < 4; ++j) {
                int m  = m0 + wm * 64 + j * 16 + n16;
                int bb = m >> 11, ss = m & (SEQ - 1);
#pragma unroll
                for (int r = 0; r < 4; ++r) {
                    int nn = n0 + wn * 64 + i * 16 + quad * 4 + r;
                    int hh = nn >> 6, dd = nn & 63;
                    Vt[((size_t)(bb * HEADS + hh) * HDIM + dd) * SEQ + ss] =
                        f2bf_rne(acc[i][j][r]);
                }
            }
    }
}

// ---------------------------------------------------------------------------
// Final projection (unchanged).
// ---------------------------------------------------------------------------
__global__ __launch_bounds__(256) void out_gemm(
    const unsigned short* __restrict__ Oh, const unsigned short* __restrict__ Ol,
    const unsigned short* __restrict__ Woh, const unsigned short* __restrict__ Wol,
    const float* __restrict__ bias, float* __restrict__ out)
{
    __shared__ __align__(16) unsigned short lds[16384];
    const int m0 = blockIdx.x * 128, n0 = blockIdx.y * 128;

    f32x4 acc[4][4];
#pragma unroll
    for (int i = 0; i < 4; ++i)
#pragma unroll
        for (int j = 0; j < 4; ++j) acc[i][j] = (f32x4){0.f, 0.f, 0.f, 0.f};

    gemm_mainloop(Woh, Wol, Oh, Ol, n0, m0, lds, acc);

    const int t = threadIdx.x;
    const int lane = t & 63, wid = t >> 6;
    const int wn = wid & 1, wm = wid >> 1;
    const int quad = lane >> 4, n16 = lane & 15;
#pragma unroll
    for (int i = 0; i < 4; ++i)
#pragma unroll
        for (int j = 0; j < 4; ++j) {
            int m  = m0 + wm * 64 + j * 16 + n16;
            int nn = n0 + wn * 64 + i * 16 + quad * 4;
            float4 v;
            v.x = acc[i][j][0] + bias[nn + 0];
            v.y = acc[i][j][1] + bias[nn + 1];
            v.z = acc[i][j][2] + bias[nn + 2];
            v.w = acc[i][j][3] + bias[nn + 3];
            *(float4*)&out[(size_t)m * HIDDEN + nn] = v;
        }
}

// ---------------------------------------------------------------------------
// Fused adaptive sparse attention, STAGED-LDS edition.
// Round-7 lesson: per-lane scattered global B-frag loads (16 lines/wave-load)
// throttle the TA/L1 pipe. Fix: coalesced global_load_lds staging (8 lines /
// wave-load) + ds_read_b128 fragments — the m97 GEMM pattern.
// Single QK pass; scores persist in sc[32] (static indexing, 128 regs).
// Chunk = 128 keys. K LDS layout: [key][16B-chunk c' = c ^ (key&7)] (swizzle
// applied on the *source* address so global_load_lds's lane-ordered LDS
// destination stays contiguous). V staged into the dead K region for PV.
// ---------------------------------------------------------------------------
__global__ __launch_bounds__(256, 2) void attn_mfma(
    const unsigned short* __restrict__ Qh, const unsigned short* __restrict__ Ql,
    const unsigned short* __restrict__ Kh, const unsigned short* __restrict__ Kl,
    const unsigned short* __restrict__ Vt, const float* __restrict__ thrp,
    unsigned short* __restrict__ Oh, unsigned short* __restrict__ Ol)
{
    __shared__ __align__(16) unsigned short Ks[16384];   // 32 KB: Kh|Kl chunk; PV reuses as Vs
    __shared__ __align__(16) unsigned char U[33792];     // hist[16][513]; later Pww[4][16][32]
    __shared__ __align__(16) float cand[16][64];
    __shared__ __align__(16) float Olds[16][64];
    __shared__ float smax[4][16], ssum[4][16];
    __shared__ unsigned csum[16][16];
    __shared__ float gmax[16], gsum[16], cutv[16];
    __shared__ int bcut[16], resid[16];
    __shared__ unsigned ccnt[16];

    const int t = threadIdx.x;
    const int lane = t & 63, wid = t >> 6;
    const int quad = lane >> 4, n16 = lane & 15;
    // XCD-local mapping: all 128 q-blocks of one bh run within one XCD window.
    const int bh = (blockIdx.x & 7) + 8 * (int)(blockIdx.x >> 10);
    const int q0 = ((blockIdx.x >> 3) & 127) * QT;
    const int row0 = quad * 4;

    unsigned* hist = (unsigned*)U;
    unsigned short* Pww = (unsigned short*)(U + wid * 1024);  // [16 q][32 keys], per-wave

    const float thv = fminf(fmaxf(thrp[0], 0.f), 1.f);

    // zero LDS (QK loop's first barrier orders it before hist atomics)
    for (int j = t; j < 16*513; j += 256) hist[j] = 0u;
    for (int j = t; j < 16*64; j += 256) ((float*)Olds)[j] = 0.f;
    if (t < 16) ccnt[t] = 0u;

    // Q A-frags
    const size_t qoff = ((size_t)bh*SEQ + q0 + n16)*HDIM + quad*8;
    bf16x8 aqh0 = *(const bf16x8*)(Qh + qoff);
    bf16x8 aqh1 = *(const bf16x8*)(Qh + qoff + 32);
    bf16x8 aql0 = *(const bf16x8*)(Ql + qoff);
    bf16x8 aql1 = *(const bf16x8*)(Ql + qoff + 32);

    const unsigned short* khb = Kh + (size_t)bh*SEQ*HDIM;
    const unsigned short* klb = Kl + (size_t)bh*SEQ*HDIM;
    unsigned short* KsH = Ks;
    unsigned short* KsL = Ks + 8192;

    // ---------------- QK^T: staged chunks of 128 keys ----------------
    // sc[c*2+i] covers keys  c*128 + wid*32 + i*16 + n16  (col=n16, row=quad*4+r)
    f32x4 sc[32];
#pragma unroll
    for (int c = 0; c < 16; ++c) {
        __syncthreads();                     // prev chunk's LDS reads done
#pragma unroll
        for (int s = 0; s < 4; ++s) {
            int idx = s*256 + t;
            int row = idx >> 3, pc = idx & 7;
            int schunk = pc ^ (row & 7);     // source-side swizzle
            const size_t goff = (size_t)(c*128 + row)*HDIM + schunk*8;
            gl2lds16(khb + goff, KsH + idx*8);
            gl2lds16(klb + goff, KsL + idx*8);
        }
        __syncthreads();                     // drain staging
#pragma unroll
        for (int i = 0; i < 2; ++i) {
            int r = wid*32 + i*16 + n16;     // local key row in chunk
            int p0 = (quad ^ (r & 7)) * 8;
            int p1 = ((quad + 4) ^ (r & 7)) * 8;
            bf16x8 kb0 = *(const bf16x8*)(KsH + r*64 + p0);
            bf16x8 kb1 = *(const bf16x8*)(KsH + r*64 + p1);
            bf16x8 kl0 = *(const bf16x8*)(KsL + r*64 + p0);
            bf16x8 kl1 = *(const bf16x8*)(KsL + r*64 + p1);
            f32x4 a = {0.f, 0.f, 0.f, 0.f};
            a = __builtin_amdgcn_mfma_f32_16x16x32_bf16(aqh0, kb0, a, 0, 0, 0);
            a = __builtin_amdgcn_mfma_f32_16x16x32_bf16(aqh1, kb1, a, 0, 0, 0);
            a = __builtin_amdgcn_mfma_f32_16x16x32_bf16(aqh0, kl0, a, 0, 0, 0);
            a = __builtin_amdgcn_mfma_f32_16x16x32_bf16(aqh1, kl1, a, 0, 0, 0);
            a = __builtin_amdgcn_mfma_f32_16x16x32_bf16(aql0, kb0, a, 0, 0, 0);
            a = __builtin_amdgcn_mfma_f32_16x16x32_bf16(aql1, kb1, a, 0, 0, 0);
            sc[c*2 + i] = a;
        }
    }

    // ---------------- rowmax ----------------
    float rmax[4];
#pragma unroll
    for (int r = 0; r < 4; ++r) {
        float v = sc[0][r];
#pragma unroll
        for (int tt = 1; tt < 32; ++tt) v = fmaxf(v, sc[tt][r]);
#pragma unroll
        for (int m = 1; m < 16; m <<= 1) v = fmaxf(v, __shfl_xor(v, m));
        rmax[r] = v;
    }
    if (n16 == 0) {
#pragma unroll
        for (int r = 0; r < 4; ++r) smax[wid][row0 + r] = rmax[r];
    }
    __syncthreads();                         // smax ready (hist zero also ordered)
    if (t < 16) gmax[t] = fmaxf(fmaxf(smax[0][t], smax[1][t]),
                                fmaxf(smax[2][t], smax[3][t]));

    // ---------------- histogram (register sweep) ----------------
#pragma unroll
    for (int tt = 0; tt < 32; ++tt)
#pragma unroll
        for (int r = 0; r < 4; ++r)
            atomicAdd(&hist[(row0 + r)*513 + score_bucket(sc[tt][r])], 1u);
    __syncthreads();

    // ---------------- chunk sums ----------------
    {
        int row = t >> 4, slot = t & 15;
        int btop = 512 - slot*32;
        unsigned s = 0;
        for (int b = btop - 32; b < btop; ++b) s += hist[row*513 + b];
        csum[row][slot] = s;
    }
    __syncthreads();

    // ---------------- scan (register-resident, t<16) ----------------
    if (t < 16) {
        unsigned cs[16];
#pragma unroll
        for (int j = 0; j < 16; ++j) cs[j] = csum[t][j];
        unsigned cum = 0; int jc = -1;
#pragma unroll
        for (int j = 0; j < 16; ++j) {
            bool here = (jc < 0) && (cum + cs[j] >= (unsigned)KSEL);
            if (here) jc = j;
            if (jc < 0) cum += cs[j];
        }
        int btop = 512 - jc*32;
        unsigned hb[32];
#pragma unroll 4
        for (int i = 0; i < 32; ++i) hb[i] = hist[t*513 + btop - 1 - i];
        unsigned c2 = cum; int bsel = btop - 32; int rres = 1; bool found = false;
#pragma unroll
        for (int i = 0; i < 32; ++i) {
            bool here = !found && (c2 + hb[i] >= (unsigned)KSEL);
            if (here) { bsel = btop - 1 - i; rres = KSEL - (int)c2; found = true; }
            if (!found) c2 += hb[i];
        }
        bcut[t] = bsel; resid[t] = rres;
        cutv[t] = ((float)bsel - 256.0f) * 0.03125f;   // fallback: bucket lower edge
    }
    __syncthreads();

    // ---------------- gather cutoff-bucket candidates (register sweep) --------
    {
        int bc[4];
#pragma unroll
        for (int r = 0; r < 4; ++r) bc[r] = bcut[row0 + r];
#pragma unroll
        for (int tt = 0; tt < 32; ++tt)
#pragma unroll
            for (int r = 0; r < 4; ++r) {
                float v = sc[tt][r];
                if (score_bucket(v) == bc[r]) {
                    unsigned idx = atomicAdd(&ccnt[row0 + r], 1u);
                    if (idx < 64u) cand[row0 + r][idx] = v;
                }
            }
    }
    __syncthreads();

    // ---------------- exact rank among candidates ----------------
    {
        int row = t >> 4, slot = t & 15;
        int n = min((int)ccnt[row], 64);
        int r = resid[row];
        for (int i = slot; i < n; i += 16) {
            float c = cand[row][i];
            int gt = 0, ge = 0;
            for (int j = 0; j < n; ++j) {
                float x = cand[row][j];
                gt += (x > c); ge += (x >= c);
            }
            if (gt < r && ge >= r) cutv[row] = c;
        }
    }
    __syncthreads();                         // hist dead; Pww region live from here

    // ---------------- softmax + PV: staged V chunks ----------------
    float mrow[4], crow[4], l4[4];
#pragma unroll
    for (int r = 0; r < 4; ++r) {
        mrow[r] = gmax[row0 + r];
        crow[r] = fmaxf(cutv[row0 + r], thv);
        l4[r] = 0.f;
    }
    f32x4 oacc[4];
#pragma unroll
    for (int dt = 0; dt < 4; ++dt) oacc[dt] = (f32x4){0.f, 0.f, 0.f, 0.f};
    const unsigned short* vtb = Vt + (size_t)bh*HDIM*SEQ;
    unsigned short* Vs = Ks;                 // alias: K staging region is dead

#pragma unroll
    for (int c = 0; c < 16; ++c) {
        __syncthreads();                     // prev chunk's Vs reads done
#pragma unroll
        for (int s = 0; s < 4; ++s) {
            int idx = s*256 + t;
            int row = idx >> 4, pc = idx & 15;
            int schunk = pc ^ (row & 15);    // source-side swizzle
            gl2lds16(vtb + (size_t)row*SEQ + c*128 + schunk*8, Vs + idx*8);
        }
        // write this chunk's P (wave-private Pww; in-wave DS ordering suffices)
#pragma unroll
        for (int i = 0; i < 2; ++i)
#pragma unroll
            for (int r = 0; r < 4; ++r) {
                float v = sc[c*2 + i][r];
                float p = (v >= crow[r]) ? __expf(v - mrow[r]) : 0.f;
                l4[r] += p;
                Pww[(row0 + r)*32 + i*16 + n16] = f2bf_rne(p);
            }
        __syncthreads();                     // drain V staging
        bf16x8 af = *(const bf16x8*)(Pww + n16*32 + quad*8);  // A[m=n16][k=quad*8+j]
#pragma unroll
        for (int dt = 0; dt < 4; ++dt) {
            int vrow = dt*16 + n16;
            int pos = ((wid*4 + quad) ^ (vrow & 15)) * 8;
            bf16x8 bf = *(const bf16x8*)(Vs + vrow*128 + pos);
            oacc[dt] = __builtin_amdgcn_mfma_f32_16x16x32_bf16(af, bf, oacc[dt], 0, 0, 0);
        }
    }

    // ---------------- reductions + writeout ----------------
#pragma unroll
    for (int r = 0; r < 4; ++r) {
#pragma unroll
        for (int m = 1; m < 16; m <<= 1) l4[r] += __shfl_xor(l4[r], m);
    }
    if (n16 == 0) {
#pragma unroll
        for (int r = 0; r < 4; ++r) ssum[wid][row0 + r] = l4[r];
    }
#pragma unroll
    for (int dt = 0; dt < 4; ++dt)
#pragma unroll
        for (int r = 0; r < 4; ++r)
            atomicAdd(&Olds[row0 + r][dt*16 + n16], oacc[dt][r]);
    __syncthreads();
    if (t < 16) gsum[t] = ssum[0][t] + ssum[1][t] + ssum[2][t] + ssum[3][t];
    __syncthreads();
    {
        int row = t >> 4, d4 = (t & 15) * 4;
        float inv = 1.0f / gsum[row];
        float o0 = Olds[row][d4+0] * inv, o1 = Olds[row][d4+1] * inv;
        float o2 = Olds[row][d4+2] * inv, o3 = Olds[row][d4+3] * inv;
        unsigned short h0 = f2bf_rne(o0), h1 = f2bf_rne(o1);
        unsigned short h2 = f2bf_rne(o2), h3 = f2bf_rne(o3);
        uint2 hv, lv;
        hv.x = (unsigned)h0 | ((unsigned)h1 << 16);
        hv.y = (unsigned)h2 | ((unsigned)h3 << 16);
        lv.x = (unsigned)f2bf_rne(o0 - bf2f(h0)) | ((unsigned)f2bf_rne(o1 - bf2f(h1)) << 16);
        lv.y = (unsigned)f2bf_rne(o2 - bf2f(h2)) | ((unsigned)f2bf_rne(o3 - bf2f(h3)) << 16);
        const int bb = bh >> 4, hh = bh & 15;
        size_t base = ((size_t)(bb*SEQ + q0 + row))*HIDDEN + hh*HDIM + d4;
        *(uint2*)(Oh + base) = hv;
        *(uint2*)(Ol + base) = lv;
    }
}

// ---------------------------------------------------------------------------
extern "C" void kernel_launch(void* const* d_in, const int* in_sizes, int n_in,
                              void* d_out, int out_size, void* d_ws, size_t ws_size,
                              hipStream_t stream)
{
    (void)in_sizes; (void)n_in; (void)out_size; (void)ws_size;
    const float* x  = (const float*)d_in[0];
    const float* Wq = (const float*)d_in[1];
    const float* Wk = (const float*)d_in[2];
    const float* Wv = (const float*)d_in[3];
    const float* Wo = (const float*)d_in[4];
    const float* bo = (const float*)d_in[5];
    const float* at = (const float*)d_in[6];
    float* out = (float*)d_out;

    char* ws = (char*)d_ws;
    const size_t MB = 1048576;
    unsigned short* xh  = (unsigned short*)(ws);            // 8 MB; later Oh
    unsigned short* xl  = (unsigned short*)(ws + 8*MB);     // 8 MB; later Ol
    unsigned short* Wsp = (unsigned short*)(ws + 16*MB);    // 16 MB: 8 x 1M ushorts
    unsigned short* Qh  = (unsigned short*)(ws + 32*MB);
    unsigned short* Ql  = (unsigned short*)(ws + 40*MB);
    unsigned short* Kh  = (unsigned short*)(ws + 48*MB);
    unsigned short* Kl  = (unsigned short*)(ws + 56*MB);
    unsigned short* Vt  = (unsigned short*)d_out;           // front 8 MB of out (dead before out_gemm)

    split_bf<<<MTOT*HIDDEN/4/256, 256, 0, stream>>>(x,  xh, xl, MTOT*HIDDEN/4);
    split_bf<<<HIDDEN*HIDDEN/4/256, 256, 0, stream>>>(Wq, Wsp + 0u*1048576u, Wsp + 1u*1048576u, HIDDEN*HIDDEN/4);
    split_bf<<<HIDDEN*HIDDEN/4/256, 256, 0, stream>>>(Wk, Wsp + 2u*1048576u, Wsp + 3u*1048576u, HIDDEN*HIDDEN/4);
    split_bf<<<HIDDEN*HIDDEN/4/256, 256, 0, stream>>>(Wv, Wsp + 4u*1048576u, Wsp + 5u*1048576u, HIDDEN*HIDDEN/4);
    split_bf<<<HIDDEN*HIDDEN/4/256, 256, 0, stream>>>(Wo, Wsp + 6u*1048576u, Wsp + 7u*1048576u, HIDDEN*HIDDEN/4);

    qkv_gemm<<<dim3(MTOT/128, HIDDEN/128, 3), 256, 0, stream>>>(xh, xl, Wsp, Qh, Ql, Kh, Kl, Vt);
    attn_mfma<<<BATCH*HEADS*(SEQ/QT), 256, 0, stream>>>(Qh, Ql, Kh, Kl, Vt, at, xh, xl);
    out_gemm<<<dim3(MTOT/128, HIDDEN/128, 1), 256, 0, stream>>>(xh, xl, Wsp + 6u*1048576u, Wsp + 7u*1048576u, bo, out);
}